// Round 15
// baseline (142.658 us; speedup 1.0000x reference)
//
#include <hip/hip_runtime.h>
#include <hip/hip_bf16.h>

typedef __attribute__((ext_vector_type(8))) short short8;
typedef __attribute__((ext_vector_type(4))) short short4v;
typedef __attribute__((ext_vector_type(4))) float f32x4;

#define S_LEN 2048
#define DM 1024
#define NH 16
#define HD 64

__device__ __forceinline__ short f2b(float f) {
    __hip_bfloat16 h = __float2bfloat16(f);
    return *reinterpret_cast<short*>(&h);
}

// ---------------- convert x (fp32 -> bf16) into A-fragment tiling (R10-proven) ----------------
__global__ void k_convert_x(const float* __restrict__ x, short* __restrict__ Af) {
    int t = blockIdx.x * 256 + threadIdx.x;       // 524288 threads: s(4096) x kc(128)
    int s = t >> 7, kc = t & 127;
    const float* xp = x + (size_t)s * DM + kc * 8;
    f32x4 v0 = *reinterpret_cast<const f32x4*>(xp);
    f32x4 v1 = *reinterpret_cast<const f32x4*>(xp + 4);
    short8 o;
    for (int e = 0; e < 4; e++) { o[e] = f2b(v0[e]); o[4 + e] = f2b(v1[e]); }
    int R = s >> 6, m = (s >> 4) & 3, lr = s & 15;
    int kstep = kc >> 3, ks = (kc >> 2) & 1, lg = kc & 3;
    size_t off = ((((size_t)(R * 16 + kstep) * 2 + ks) * 4 + m) * 64 + lg * 16 + lr) * 8;
    *reinterpret_cast<short8*>(Af + off) = o;
}

// ---------------- transpose + convert all four W into B-fragment tiling (R12-proven) ----------------
__global__ void k_transpose_w4(const float* __restrict__ W0, const float* __restrict__ W1,
                               const float* __restrict__ W2, const float* __restrict__ W3,
                               short* __restrict__ T0, short* __restrict__ T1,
                               short* __restrict__ T2, short* __restrict__ T3) {
    __shared__ float tile[32][33];
    const int z = blockIdx.z;
    const float* W = (z == 0) ? W0 : (z == 1) ? W1 : (z == 2) ? W2 : W3;
    short* Wt = (z == 0) ? T0 : (z == 1) ? T1 : (z == 2) ? T2 : T3;
    int tx = threadIdx.x, ty = threadIdx.y;
    int nb = blockIdx.x * 32, kb = blockIdx.y * 32;
    for (int i = 0; i < 4; i++)
        tile[ty + i * 8][tx] = W[(size_t)(kb + ty + i * 8) * DM + nb + tx];
    __syncthreads();
    if (ty < 4) {
        int col = nb + tx;
        int k0 = kb + ty * 8;
        short8 o;
#pragma unroll
        for (int e = 0; e < 8; e++) o[e] = f2b(tile[ty * 8 + e][tx]);
        int C = col >> 6, n = (col >> 4) & 3, lr = col & 15;
        int kstep = k0 >> 6, ksb = (k0 >> 5) & 1, lg = (k0 >> 3) & 3;
        *reinterpret_cast<short8*>(
            &Wt[((((size_t)(C * 16 + kstep) * 2 + ksb) * 4 + n) * 64 + lg * 16 + lr) * 8]) = o;
    }
}

// ---------------- fused QKV GEMM: NO LDS, 1-wave blocks, 2 R-blocks per wave ----------------
// grid 1536 x 64thr. Wave = (Rpair, z, C): computes rows [Rp*128, Rp*128+128) x col-block C.
// B fragments are read ONCE per 2 R-blocks -> B L3 traffic halved vs R13 (B doesn't fit L2;
// A slice fits L2 so A re-reads are cheap). Epilogue = R13-proven formulas looped over rr.
__global__ __launch_bounds__(64) void k_gemm_qkv(
    const short* __restrict__ Af,
    const short* __restrict__ Bq, const short* __restrict__ Bk, const short* __restrict__ Bv,
    const float* __restrict__ bq, const float* __restrict__ bk, const float* __restrict__ bv,
    short* __restrict__ Qb, short* __restrict__ Kfrag, short* __restrict__ Vfrag,
    float* __restrict__ pK, float* __restrict__ pV)
{
    const int bid = blockIdx.x;
    const int orig = (bid & 7) * 192 + (bid >> 3);   // XCD-chunked: R in [8x, 8x+8)
    const int Rp = orig / 48;
    const int rem = orig - Rp * 48;
    const int z = rem >> 4, C = rem & 15;
    const short* Bf = (z == 0) ? Bq : (z == 1) ? Bk : Bv;
    const float* bias = (z == 0) ? bq : (z == 1) ? bk : bv;
    const int l = threadIdx.x;
    const int lr = l & 15, lg = l >> 4;

    f32x4 acc[2][4][4];
#pragma unroll
    for (int rr = 0; rr < 2; rr++)
#pragma unroll
        for (int m = 0; m < 4; m++)
#pragma unroll
            for (int n = 0; n < 4; n++) acc[rr][m][n] = (f32x4)0.0f;

    const short* ap0 = Af + (size_t)(Rp * 2) * 16 * 4096 + l * 8;
    const short* ap1 = ap0 + 16 * 4096;
    const short* bp  = Bf + (size_t)C * 16 * 4096 + l * 8;

#pragma unroll 1
    for (int kstep = 0; kstep < 16; ++kstep) {
#pragma unroll
        for (int ks = 0; ks < 2; ks++) {
            short8 a0[4], a1[4], b[4];
#pragma unroll
            for (int i = 0; i < 4; i++) {
                a0[i] = *reinterpret_cast<const short8*>(ap0 + (ks * 4 + i) * 512);
                a1[i] = *reinterpret_cast<const short8*>(ap1 + (ks * 4 + i) * 512);
                b[i]  = *reinterpret_cast<const short8*>(bp  + (ks * 4 + i) * 512);
            }
#pragma unroll
            for (int m = 0; m < 4; m++)
#pragma unroll
                for (int n = 0; n < 4; n++) {
                    acc[0][m][n] = __builtin_amdgcn_mfma_f32_16x16x32_bf16(a0[m], b[n], acc[0][m][n], 0, 0, 0);
                    acc[1][m][n] = __builtin_amdgcn_mfma_f32_16x16x32_bf16(a1[m], b[n], acc[1][m][n], 0, 0, 0);
                }
        }
        ap0 += 4096; ap1 += 4096; bp += 4096;
    }

    for (int rr = 0; rr < 2; rr++) {
        const int R = Rp * 2 + rr;
        for (int m = 0; m < 4; m++)
            for (int n = 0; n < 4; n++) {
                int row = R * 64 + m * 16 + lg * 4;
                int col = C * 64 + n * 16 + lr;
                float bv_ = bias[col];
                int b_ = row >> 11, sI0 = row & 2047, hI = col >> 6, dh = col & 63;
                if (z == 0) {
                    for (int r = 0; r < 4; r++) {
                        float v = acc[rr][m][n][r] + bv_;
                        Qb[(size_t)(row + r) * DM + col] = f2b(v * 0.0450842200575152f);  // 1/32*log2(e)
                    }
                } else if (z == 1) {
                    for (int r = 0; r < 4; r++) {
                        float v = acc[rr][m][n][r] + bv_;
                        int sI = sI0 + r;
                        pK[(((size_t)(b_ * NH + hI)) * S_LEN + sI) * HD + dh] = v;
                        int j = sI >> 6, kk = sI & 63;
                        int cg = ((kk >> 4) & 2) | ((kk >> 2) & 1);
                        int lrA = ((kk >> 3) & 3) * 4 + (kk & 3);
                        int lane = lrA + ((dh >> 3) & 3) * 16;
                        int ks = dh >> 5, e = dh & 7;
                        Kfrag[((((size_t)(b_ * NH + hI) * 32 + j) * 2 + ks) * 4 + cg) * 512
                              + lane * 8 + e] = f2b(v);
                    }
                } else {
                    int j = sI0 >> 6, ks = (sI0 >> 5) & 1;
                    int dg = dh >> 4;
                    int lane = (dh & 15) + ((sI0 >> 3) & 3) * 16;
                    int e0 = sI0 & 7;
                    short4v tv;
                    for (int r = 0; r < 4; r++) {
                        float v = acc[rr][m][n][r] + bv_;
                        pV[(((size_t)(b_ * NH + hI)) * S_LEN + (sI0 + r)) * HD + dh] = v;
                        tv[r] = f2b(v);
                    }
                    *reinterpret_cast<short4v*>(
                        &Vfrag[((((size_t)(b_ * NH + hI) * 32 + j) * 2 + ks) * 4 + dg) * 512
                               + lane * 8 + e0]) = tv;
                }
            }
    }
}

// ---------------- final GEMM: out = attn @ Wo + bo — NO LDS fragment version (R11-proven) ----------------
__global__ __launch_bounds__(64) void k_gemm_o(
    const short* __restrict__ Af, const short* __restrict__ Bf,
    const float* __restrict__ bo, float* __restrict__ out)
{
    const int bid = blockIdx.x;
    const int orig = (bid & 7) * 128 + (bid >> 3);
    const int R = orig >> 4, C = orig & 15;
    const int l = threadIdx.x;
    const int lr = l & 15, lg = l >> 4;

    f32x4 acc[4][4];
#pragma unroll
    for (int m = 0; m < 4; m++)
#pragma unroll
        for (int n = 0; n < 4; n++) acc[m][n] = (f32x4)0.0f;

    const short* ap = Af + (size_t)R * 16 * 4096 + l * 8;
    const short* bp = Bf + (size_t)C * 16 * 4096 + l * 8;

#pragma unroll 1
    for (int kstep = 0; kstep < 16; ++kstep) {
        short8 a[2][4], b[2][4];
#pragma unroll
        for (int ks = 0; ks < 2; ks++)
#pragma unroll
            for (int i = 0; i < 4; i++) {
                a[ks][i] = *reinterpret_cast<const short8*>(ap + (ks * 4 + i) * 512);
                b[ks][i] = *reinterpret_cast<const short8*>(bp + (ks * 4 + i) * 512);
            }
        ap += 4096; bp += 4096;
#pragma unroll
        for (int ks = 0; ks < 2; ks++)
#pragma unroll
            for (int m = 0; m < 4; m++)
#pragma unroll
                for (int n = 0; n < 4; n++)
                    acc[m][n] = __builtin_amdgcn_mfma_f32_16x16x32_bf16(a[ks][m], b[ks][n], acc[m][n], 0, 0, 0);
    }
    for (int m = 0; m < 4; m++)
        for (int n = 0; n < 4; n++) {
            int row = R * 64 + m * 16 + lg * 4;
            int col = C * 64 + n * 16 + lr;
            float bv_ = bo[col];
            for (int r = 0; r < 4; r++)
                out[(size_t)(row + r) * DM + col] = acc[m][n][r] + bv_;
        }
}

// ---------------- causal flash attention: 2 adjacent strips per 1-wave block (R13-proven) ----------------
__global__ __launch_bounds__(64) void k_attn(
    const short* __restrict__ Qb, const short* __restrict__ Kfrag,
    const short* __restrict__ Vfrag, short* __restrict__ Afo)
{
    const int bid = blockIdx.x;
    const int orig = (bid & 7) * 256 + (bid >> 3);   // XCD-chunked: 4 bh per XCD
    const int bh = orig >> 6;
    const int p = 63 - (orig & 63);                  // heavy pairs dispatch first
    const int h = bh & 15, b = bh >> 4;
    const int l = threadIdx.x;
    const int lr = l & 15, lg = l >> 4;
    const short* Qp = Qb + (size_t)b * S_LEN * DM + (size_t)h * HD;
    const short* Kbh = Kfrag + (size_t)bh * 32 * 4096;
    const short* Vbh = Vfrag + (size_t)bh * 32 * 4096;

    const int jmax = p >> 1;
    const int sA = 2 * p, sB = 2 * p + 1;
    const int qrowA = sA * 16 + lr, qrowB = sB * 16 + lr;
    short8 qfA0 = *reinterpret_cast<const short8*>(Qp + (size_t)qrowA * DM + lg * 8);
    short8 qfA1 = *reinterpret_cast<const short8*>(Qp + (size_t)qrowA * DM + 32 + lg * 8);
    short8 qfB0 = *reinterpret_cast<const short8*>(Qp + (size_t)qrowB * DM + lg * 8);
    short8 qfB1 = *reinterpret_cast<const short8*>(Qp + (size_t)qrowB * DM + 32 + lg * 8);
    f32x4 oA[4], oB[4];
#pragma unroll
    for (int dg = 0; dg < 4; dg++) { oA[dg] = (f32x4)0.0f; oB[dg] = (f32x4)0.0f; }
    float lrunA = 0.0f, lrunB = 0.0f;

    const short* kp = Kbh + l * 8;
    const short* vp = Vbh + l * 8;
    short8 kc[2][4], vc[2][4];
#pragma unroll
    for (int ks = 0; ks < 2; ks++)
#pragma unroll
        for (int cg = 0; cg < 4; cg++) {
            kc[ks][cg] = *reinterpret_cast<const short8*>(kp + (ks * 4 + cg) * 512);
            vc[ks][cg] = *reinterpret_cast<const short8*>(vp + (ks * 4 + cg) * 512);
        }

    for (int j = 0; j <= jmax; ++j) {
        f32x4 sAcc[4], sBcc[4];
#pragma unroll
        for (int cg = 0; cg < 4; cg++) { sAcc[cg] = (f32x4)0.0f; sBcc[cg] = (f32x4)0.0f; }
#pragma unroll
        for (int ks = 0; ks < 2; ks++) {
            const short8 qfa = ks ? qfA1 : qfA0;
            const short8 qfb = ks ? qfB1 : qfB0;
#pragma unroll
            for (int cg = 0; cg < 4; cg++) {
                sAcc[cg] = __builtin_amdgcn_mfma_f32_16x16x32_bf16(kc[ks][cg], qfa, sAcc[cg], 0, 0, 0);
                sBcc[cg] = __builtin_amdgcn_mfma_f32_16x16x32_bf16(kc[ks][cg], qfb, sBcc[cg], 0, 0, 0);
            }
        }
        if (j < jmax) {
            kp += 4096;
#pragma unroll
            for (int ks = 0; ks < 2; ks++)
#pragma unroll
                for (int cg = 0; cg < 4; cg++)
                    kc[ks][cg] = *reinterpret_cast<const short8*>(kp + (ks * 4 + cg) * 512);
        }
        if (j == jmax) {
#pragma unroll
            for (int cg = 0; cg < 4; cg++)
#pragma unroll
                for (int r = 0; r < 4; r++) {
                    int n = ((cg >> 1) << 5) + (lg << 3) + ((cg & 1) << 2) + r;
                    if (j * 64 + n > qrowA) sAcc[cg][r] = -INFINITY;
                    if (j * 64 + n > qrowB) sBcc[cg][r] = -INFINITY;
                }
        }
        float rsA = 0.0f, rsB = 0.0f;
#pragma unroll
        for (int cg = 0; cg < 4; cg++)
#pragma unroll
            for (int r = 0; r < 4; r++) {
                float pa = __builtin_amdgcn_exp2f(sAcc[cg][r]);
                float pb = __builtin_amdgcn_exp2f(sBcc[cg][r]);
                sAcc[cg][r] = pa; sBcc[cg][r] = pb;
                rsA += pa; rsB += pb;
            }
        lrunA += rsA; lrunB += rsB;
        short8 pfA0, pfA1, pfB0, pfB1;
#pragma unroll
        for (int r = 0; r < 4; r++) {
            pfA0[r] = f2b(sAcc[0][r]); pfA0[4 + r] = f2b(sAcc[1][r]);
            pfA1[r] = f2b(sAcc[2][r]); pfA1[4 + r] = f2b(sAcc[3][r]);
            pfB0[r] = f2b(sBcc[0][r]); pfB0[4 + r] = f2b(sBcc[1][r]);
            pfB1[r] = f2b(sBcc[2][r]); pfB1[4 + r] = f2b(sBcc[3][r]);
        }
#pragma unroll
        for (int ks = 0; ks < 2; ks++) {
            const short8 pfa = ks ? pfA1 : pfA0;
            const short8 pfb = ks ? pfB1 : pfB0;
#pragma unroll
            for (int dg = 0; dg < 4; dg++) {
                oA[dg] = __builtin_amdgcn_mfma_f32_16x16x32_bf16(vc[ks][dg], pfa, oA[dg], 0, 0, 0);
                oB[dg] = __builtin_amdgcn_mfma_f32_16x16x32_bf16(vc[ks][dg], pfb, oB[dg], 0, 0, 0);
            }
        }
        if (j < jmax) {
            vp += 4096;
#pragma unroll
            for (int ks = 0; ks < 2; ks++)
#pragma unroll
                for (int cg = 0; cg < 4; cg++)
                    vc[ks][cg] = *reinterpret_cast<const short8*>(vp + (ks * 4 + cg) * 512);
        }
    }
    lrunA += __shfl_xor(lrunA, 16); lrunA += __shfl_xor(lrunA, 32);
    lrunB += __shfl_xor(lrunB, 16); lrunB += __shfl_xor(lrunB, 32);
    float rinvA = 1.0f / lrunA, rinvB = 1.0f / lrunB;
    const size_t RoA = (size_t)(b * 32 + (sA >> 2));
    const int moA = sA & 3, moB = sB & 3;
#pragma unroll
    for (int dg = 0; dg < 4; dg++) {
        short4v ovA, ovB;
#pragma unroll
        for (int r = 0; r < 4; r++) {
            ovA[r] = f2b(oA[dg][r] * rinvA);
            ovB[r] = f2b(oB[dg][r] * rinvB);
        }
        int lane_o = ((dg & 1) * 2 + (lg >> 1)) * 16 + lr;
        size_t offA = (((RoA * 16 + h) * 2 + (dg >> 1)) * 4 + moA) * 512
                      + (size_t)lane_o * 8 + (lg & 1) * 4;
        size_t offB = (((RoA * 16 + h) * 2 + (dg >> 1)) * 4 + moB) * 512
                      + (size_t)lane_o * 8 + (lg & 1) * 4;
        *reinterpret_cast<short4v*>(Afo + offA) = ovA;
        *reinterpret_cast<short4v*>(Afo + offB) = ovB;
    }
}

extern "C" void kernel_launch(void* const* d_in, const int* in_sizes, int n_in,
                              void* d_out, int out_size, void* d_ws, size_t ws_size,
                              hipStream_t stream) {
    const float* x  = (const float*)d_in[0];
    const float* Wq = (const float*)d_in[1];
    const float* bq = (const float*)d_in[2];
    const float* Wk = (const float*)d_in[3];
    const float* bk = (const float*)d_in[4];
    const float* Wv = (const float*)d_in[5];
    const float* bv = (const float*)d_in[6];
    const float* Wo = (const float*)d_in[7];
    const float* bo = (const float*)d_in[8];

    float* out = (float*)d_out;
    float* presentK = out + (size_t)4194304;
    float* presentV = presentK + (size_t)4194304;

    char* ws = (char*)d_ws;
    short* Af    = (short*)(ws);                        // x in A-frag tiling, 8MB
    short* Bfq   = (short*)(ws + ((size_t)8  << 20));   // W in B-frag tiling, 2MB each
    short* Bfk   = (short*)(ws + ((size_t)10 << 20));
    short* Bfv   = (short*)(ws + ((size_t)12 << 20));
    short* Bfo   = (short*)(ws + ((size_t)14 << 20));
    short* Qb    = (short*)(ws + ((size_t)16 << 20));
    short* Kfrag = (short*)(ws + ((size_t)24 << 20));   // [bh][j][ks][cg][lane][8] bf16, 8MB
    short* Vfrag = (short*)(ws + ((size_t)32 << 20));   // [bh][j][ks][dg][lane][8] bf16, 8MB
    short* Afo   = (short*)(ws + ((size_t)40 << 20));   // attn out in A-frag tiling, 8MB

    k_convert_x<<<dim3(2048), dim3(256), 0, stream>>>(x, Af);
    k_transpose_w4<<<dim3(32, 32, 4), dim3(32, 8), 0, stream>>>(
        Wq, Wk, Wv, Wo, Bfq, Bfk, Bfv, Bfo);
    k_gemm_qkv<<<dim3(1536), dim3(64), 0, stream>>>(
        Af, Bfq, Bfk, Bfv, bq, bk, bv, Qb, Kfrag, Vfrag, presentK, presentV);
    k_attn<<<dim3(2048), dim3(64), 0, stream>>>(Qb, Kfrag, Vfrag, Afo);
    k_gemm_o<<<dim3(1024), dim3(64), 0, stream>>>(Afo, Bfo, bo, out);
}

// Round 16
// 131.750 us; speedup vs baseline: 1.0828x; 1.0828x over previous
//
#include <hip/hip_runtime.h>
#include <hip/hip_bf16.h>

typedef __attribute__((ext_vector_type(8))) short short8;
typedef __attribute__((ext_vector_type(4))) short short4v;
typedef __attribute__((ext_vector_type(4))) float f32x4;

#define S_LEN 2048
#define DM 1024
#define NH 16
#define HD 64

__device__ __forceinline__ short f2b(float f) {
    __hip_bfloat16 h = __float2bfloat16(f);
    return *reinterpret_cast<short*>(&h);
}

__device__ __forceinline__ void gload_lds16(const void* g, void* l) {
    __builtin_amdgcn_global_load_lds(
        (const __attribute__((address_space(1))) unsigned int*)g,
        (__attribute__((address_space(3))) unsigned int*)l, 16, 0, 0);
}

// ---------------- convert x (fp32 -> bf16) into A-fragment tiling (R10-proven) ----------------
__global__ void k_convert_x(const float* __restrict__ x, short* __restrict__ Af) {
    int t = blockIdx.x * 256 + threadIdx.x;       // 524288 threads: s(4096) x kc(128)
    int s = t >> 7, kc = t & 127;
    const float* xp = x + (size_t)s * DM + kc * 8;
    f32x4 v0 = *reinterpret_cast<const f32x4*>(xp);
    f32x4 v1 = *reinterpret_cast<const f32x4*>(xp + 4);
    short8 o;
    for (int e = 0; e < 4; e++) { o[e] = f2b(v0[e]); o[4 + e] = f2b(v1[e]); }
    int R = s >> 6, m = (s >> 4) & 3, lr = s & 15;
    int kstep = kc >> 3, ks = (kc >> 2) & 1, lg = kc & 3;
    size_t off = ((((size_t)(R * 16 + kstep) * 2 + ks) * 4 + m) * 64 + lg * 16 + lr) * 8;
    *reinterpret_cast<short8*>(Af + off) = o;
}

// ---------------- transpose + convert all four W into B-fragment tiling (R12-proven) ----------------
__global__ void k_transpose_w4(const float* __restrict__ W0, const float* __restrict__ W1,
                               const float* __restrict__ W2, const float* __restrict__ W3,
                               short* __restrict__ T0, short* __restrict__ T1,
                               short* __restrict__ T2, short* __restrict__ T3) {
    __shared__ float tile[32][33];
    const int z = blockIdx.z;
    const float* W = (z == 0) ? W0 : (z == 1) ? W1 : (z == 2) ? W2 : W3;
    short* Wt = (z == 0) ? T0 : (z == 1) ? T1 : (z == 2) ? T2 : T3;
    int tx = threadIdx.x, ty = threadIdx.y;
    int nb = blockIdx.x * 32, kb = blockIdx.y * 32;
    for (int i = 0; i < 4; i++)
        tile[ty + i * 8][tx] = W[(size_t)(kb + ty + i * 8) * DM + nb + tx];
    __syncthreads();
    if (ty < 4) {
        int col = nb + tx;
        int k0 = kb + ty * 8;
        short8 o;
#pragma unroll
        for (int e = 0; e < 8; e++) o[e] = f2b(tile[ty * 8 + e][tx]);
        int C = col >> 6, n = (col >> 4) & 3, lr = col & 15;
        int kstep = k0 >> 6, ksb = (k0 >> 5) & 1, lg = (k0 >> 3) & 3;
        *reinterpret_cast<short8*>(
            &Wt[((((size_t)(C * 16 + kstep) * 2 + ksb) * 4 + n) * 64 + lg * 16 + lr) * 8]) = o;
    }
}

// ---------------- fused QKV GEMM: 4-wave blocks; B staged in LDS (shared), A from L2 ----------------
// grid 768 x 256thr. Block = (Rg, z, C); wave w computes R = Rg*4+w.
// B's 8KB kstep tile is staged ONCE per block (global_load_lds, double-buffered, 1 barrier/kstep)
// -> B L2/L3 traffic /4; A slice (1MB/XCD) is L2-resident. Per-wave math = R10/R13-proven body.
__global__ __launch_bounds__(256) void k_gemm_qkv(
    const short* __restrict__ Af,
    const short* __restrict__ Bq, const short* __restrict__ Bk, const short* __restrict__ Bv,
    const float* __restrict__ bq, const float* __restrict__ bk, const float* __restrict__ bv,
    short* __restrict__ Qb, short* __restrict__ Kfrag, short* __restrict__ Vfrag,
    float* __restrict__ pK, float* __restrict__ pV)
{
    __shared__ alignas(16) short Bs[2][4096];
    const int bid = blockIdx.x;
    const int orig = (bid & 7) * 96 + (bid >> 3);    // XCD-chunked: Rg in {2x, 2x+1} -> R in [8x,8x+8)
    const int Rg = orig / 48;
    const int rem = orig - Rg * 48;
    const int z = rem >> 4, C = rem & 15;
    const short* Bf = (z == 0) ? Bq : (z == 1) ? Bk : Bv;
    const float* bias = (z == 0) ? bq : (z == 1) ? bk : bv;
    const int w = threadIdx.x >> 6, l = threadIdx.x & 63;
    const int R = Rg * 4 + w;
    const int lr = l & 15, lg = l >> 4;

    f32x4 acc[4][4];
#pragma unroll
    for (int m = 0; m < 4; m++)
#pragma unroll
        for (int n = 0; n < 4; n++) acc[m][n] = (f32x4)0.0f;

    const short* ap = Af + (size_t)R * 16 * 4096 + l * 8;
    const short* bp = Bf + (size_t)C * 16 * 4096;

    // prologue: stage kstep 0 into Bs[0] (256 thr x 2 x 16B = 8KB)
#pragma unroll
    for (int p = 0; p < 2; p++) {
        int idx = p * 256 + threadIdx.x;
        gload_lds16(bp + idx * 8, &Bs[0][0] + idx * 8);
    }

#pragma unroll 1
    for (int kstep = 0; kstep < 16; ++kstep) {
        const int cur = kstep & 1;
        __syncthreads();                      // Bs[cur] ready (barrier drains vmcnt)
        if (kstep < 15) {                     // stage next tile into the other buffer
            const short* bn = bp + (kstep + 1) * 4096;
#pragma unroll
            for (int p = 0; p < 2; p++) {
                int idx = p * 256 + threadIdx.x;
                gload_lds16(bn + idx * 8, &Bs[cur ^ 1][0] + idx * 8);
            }
        }
        short8 a[2][4], b[2][4];
#pragma unroll
        for (int ks = 0; ks < 2; ks++)
#pragma unroll
            for (int i = 0; i < 4; i++) {
                a[ks][i] = *reinterpret_cast<const short8*>(ap + (ks * 4 + i) * 512);
                b[ks][i] = *reinterpret_cast<const short8*>(&Bs[cur][(ks * 4 + i) * 512 + l * 8]);
            }
        ap += 4096;
#pragma unroll
        for (int ks = 0; ks < 2; ks++)
#pragma unroll
            for (int m = 0; m < 4; m++)
#pragma unroll
                for (int n = 0; n < 4; n++)
                    acc[m][n] = __builtin_amdgcn_mfma_f32_16x16x32_bf16(a[ks][m], b[ks][n], acc[m][n], 0, 0, 0);
    }

    // epilogue (R13-proven formulas)
    for (int m = 0; m < 4; m++)
        for (int n = 0; n < 4; n++) {
            int row = R * 64 + m * 16 + lg * 4;
            int col = C * 64 + n * 16 + lr;
            float bv_ = bias[col];
            int b_ = row >> 11, sI0 = row & 2047, hI = col >> 6, dh = col & 63;
            if (z == 0) {
                for (int r = 0; r < 4; r++) {
                    float v = acc[m][n][r] + bv_;
                    Qb[(size_t)(row + r) * DM + col] = f2b(v * 0.0450842200575152f);  // 1/32*log2(e)
                }
            } else if (z == 1) {
                for (int r = 0; r < 4; r++) {
                    float v = acc[m][n][r] + bv_;
                    int sI = sI0 + r;
                    pK[(((size_t)(b_ * NH + hI)) * S_LEN + sI) * HD + dh] = v;
                    int j = sI >> 6, kk = sI & 63;
                    int cg = ((kk >> 4) & 2) | ((kk >> 2) & 1);
                    int lrA = ((kk >> 3) & 3) * 4 + (kk & 3);
                    int lane = lrA + ((dh >> 3) & 3) * 16;
                    int ks = dh >> 5, e = dh & 7;
                    Kfrag[((((size_t)(b_ * NH + hI) * 32 + j) * 2 + ks) * 4 + cg) * 512
                          + lane * 8 + e] = f2b(v);
                }
            } else {
                int j = sI0 >> 6, ks = (sI0 >> 5) & 1;
                int dg = dh >> 4;
                int lane = (dh & 15) + ((sI0 >> 3) & 3) * 16;
                int e0 = sI0 & 7;
                short4v tv;
                for (int r = 0; r < 4; r++) {
                    float v = acc[m][n][r] + bv_;
                    pV[(((size_t)(b_ * NH + hI)) * S_LEN + (sI0 + r)) * HD + dh] = v;
                    tv[r] = f2b(v);
                }
                *reinterpret_cast<short4v*>(
                    &Vfrag[((((size_t)(b_ * NH + hI) * 32 + j) * 2 + ks) * 4 + dg) * 512
                           + lane * 8 + e0]) = tv;
            }
        }
}

// ---------------- final GEMM: out = attn @ Wo + bo — NO LDS fragment version (R11-proven) ----------------
__global__ __launch_bounds__(64) void k_gemm_o(
    const short* __restrict__ Af, const short* __restrict__ Bf,
    const float* __restrict__ bo, float* __restrict__ out)
{
    const int bid = blockIdx.x;
    const int orig = (bid & 7) * 128 + (bid >> 3);
    const int R = orig >> 4, C = orig & 15;
    const int l = threadIdx.x;
    const int lr = l & 15, lg = l >> 4;

    f32x4 acc[4][4];
#pragma unroll
    for (int m = 0; m < 4; m++)
#pragma unroll
        for (int n = 0; n < 4; n++) acc[m][n] = (f32x4)0.0f;

    const short* ap = Af + (size_t)R * 16 * 4096 + l * 8;
    const short* bp = Bf + (size_t)C * 16 * 4096 + l * 8;

#pragma unroll 1
    for (int kstep = 0; kstep < 16; ++kstep) {
        short8 a[2][4], b[2][4];
#pragma unroll
        for (int ks = 0; ks < 2; ks++)
#pragma unroll
            for (int i = 0; i < 4; i++) {
                a[ks][i] = *reinterpret_cast<const short8*>(ap + (ks * 4 + i) * 512);
                b[ks][i] = *reinterpret_cast<const short8*>(bp + (ks * 4 + i) * 512);
            }
        ap += 4096; bp += 4096;
#pragma unroll
        for (int ks = 0; ks < 2; ks++)
#pragma unroll
            for (int m = 0; m < 4; m++)
#pragma unroll
                for (int n = 0; n < 4; n++)
                    acc[m][n] = __builtin_amdgcn_mfma_f32_16x16x32_bf16(a[ks][m], b[ks][n], acc[m][n], 0, 0, 0);
    }
    for (int m = 0; m < 4; m++)
        for (int n = 0; n < 4; n++) {
            int row = R * 64 + m * 16 + lg * 4;
            int col = C * 64 + n * 16 + lr;
            float bv_ = bo[col];
            for (int r = 0; r < 4; r++)
                out[(size_t)(row + r) * DM + col] = acc[m][n][r] + bv_;
        }
}

// ---------------- causal flash attention: 2 adjacent strips per 1-wave block (R13-proven) ----------------
__global__ __launch_bounds__(64) void k_attn(
    const short* __restrict__ Qb, const short* __restrict__ Kfrag,
    const short* __restrict__ Vfrag, short* __restrict__ Afo)
{
    const int bid = blockIdx.x;
    const int orig = (bid & 7) * 256 + (bid >> 3);   // XCD-chunked: 4 bh per XCD
    const int bh = orig >> 6;
    const int p = 63 - (orig & 63);                  // heavy pairs dispatch first
    const int h = bh & 15, b = bh >> 4;
    const int l = threadIdx.x;
    const int lr = l & 15, lg = l >> 4;
    const short* Qp = Qb + (size_t)b * S_LEN * DM + (size_t)h * HD;
    const short* Kbh = Kfrag + (size_t)bh * 32 * 4096;
    const short* Vbh = Vfrag + (size_t)bh * 32 * 4096;

    const int jmax = p >> 1;
    const int sA = 2 * p, sB = 2 * p + 1;
    const int qrowA = sA * 16 + lr, qrowB = sB * 16 + lr;
    short8 qfA0 = *reinterpret_cast<const short8*>(Qp + (size_t)qrowA * DM + lg * 8);
    short8 qfA1 = *reinterpret_cast<const short8*>(Qp + (size_t)qrowA * DM + 32 + lg * 8);
    short8 qfB0 = *reinterpret_cast<const short8*>(Qp + (size_t)qrowB * DM + lg * 8);
    short8 qfB1 = *reinterpret_cast<const short8*>(Qp + (size_t)qrowB * DM + 32 + lg * 8);
    f32x4 oA[4], oB[4];
#pragma unroll
    for (int dg = 0; dg < 4; dg++) { oA[dg] = (f32x4)0.0f; oB[dg] = (f32x4)0.0f; }
    float lrunA = 0.0f, lrunB = 0.0f;

    const short* kp = Kbh + l * 8;
    const short* vp = Vbh + l * 8;
    short8 kc[2][4], vc[2][4];
#pragma unroll
    for (int ks = 0; ks < 2; ks++)
#pragma unroll
        for (int cg = 0; cg < 4; cg++) {
            kc[ks][cg] = *reinterpret_cast<const short8*>(kp + (ks * 4 + cg) * 512);
            vc[ks][cg] = *reinterpret_cast<const short8*>(vp + (ks * 4 + cg) * 512);
        }

    for (int j = 0; j <= jmax; ++j) {
        f32x4 sAcc[4], sBcc[4];
#pragma unroll
        for (int cg = 0; cg < 4; cg++) { sAcc[cg] = (f32x4)0.0f; sBcc[cg] = (f32x4)0.0f; }
#pragma unroll
        for (int ks = 0; ks < 2; ks++) {
            const short8 qfa = ks ? qfA1 : qfA0;
            const short8 qfb = ks ? qfB1 : qfB0;
#pragma unroll
            for (int cg = 0; cg < 4; cg++) {
                sAcc[cg] = __builtin_amdgcn_mfma_f32_16x16x32_bf16(kc[ks][cg], qfa, sAcc[cg], 0, 0, 0);
                sBcc[cg] = __builtin_amdgcn_mfma_f32_16x16x32_bf16(kc[ks][cg], qfb, sBcc[cg], 0, 0, 0);
            }
        }
        if (j < jmax) {
            kp += 4096;
#pragma unroll
            for (int ks = 0; ks < 2; ks++)
#pragma unroll
                for (int cg = 0; cg < 4; cg++)
                    kc[ks][cg] = *reinterpret_cast<const short8*>(kp + (ks * 4 + cg) * 512);
        }
        if (j == jmax) {
#pragma unroll
            for (int cg = 0; cg < 4; cg++)
#pragma unroll
                for (int r = 0; r < 4; r++) {
                    int n = ((cg >> 1) << 5) + (lg << 3) + ((cg & 1) << 2) + r;
                    if (j * 64 + n > qrowA) sAcc[cg][r] = -INFINITY;
                    if (j * 64 + n > qrowB) sBcc[cg][r] = -INFINITY;
                }
        }
        float rsA = 0.0f, rsB = 0.0f;
#pragma unroll
        for (int cg = 0; cg < 4; cg++)
#pragma unroll
            for (int r = 0; r < 4; r++) {
                float pa = __builtin_amdgcn_exp2f(sAcc[cg][r]);
                float pb = __builtin_amdgcn_exp2f(sBcc[cg][r]);
                sAcc[cg][r] = pa; sBcc[cg][r] = pb;
                rsA += pa; rsB += pb;
            }
        lrunA += rsA; lrunB += rsB;
        short8 pfA0, pfA1, pfB0, pfB1;
#pragma unroll
        for (int r = 0; r < 4; r++) {
            pfA0[r] = f2b(sAcc[0][r]); pfA0[4 + r] = f2b(sAcc[1][r]);
            pfA1[r] = f2b(sAcc[2][r]); pfA1[4 + r] = f2b(sAcc[3][r]);
            pfB0[r] = f2b(sBcc[0][r]); pfB0[4 + r] = f2b(sBcc[1][r]);
            pfB1[r] = f2b(sBcc[2][r]); pfB1[4 + r] = f2b(sBcc[3][r]);
        }
#pragma unroll
        for (int ks = 0; ks < 2; ks++) {
            const short8 pfa = ks ? pfA1 : pfA0;
            const short8 pfb = ks ? pfB1 : pfB0;
#pragma unroll
            for (int dg = 0; dg < 4; dg++) {
                oA[dg] = __builtin_amdgcn_mfma_f32_16x16x32_bf16(vc[ks][dg], pfa, oA[dg], 0, 0, 0);
                oB[dg] = __builtin_amdgcn_mfma_f32_16x16x32_bf16(vc[ks][dg], pfb, oB[dg], 0, 0, 0);
            }
        }
        if (j < jmax) {
            vp += 4096;
#pragma unroll
            for (int ks = 0; ks < 2; ks++)
#pragma unroll
                for (int cg = 0; cg < 4; cg++)
                    vc[ks][cg] = *reinterpret_cast<const short8*>(vp + (ks * 4 + cg) * 512);
        }
    }
    lrunA += __shfl_xor(lrunA, 16); lrunA += __shfl_xor(lrunA, 32);
    lrunB += __shfl_xor(lrunB, 16); lrunB += __shfl_xor(lrunB, 32);
    float rinvA = 1.0f / lrunA, rinvB = 1.0f / lrunB;
    const size_t RoA = (size_t)(b * 32 + (sA >> 2));
    const int moA = sA & 3, moB = sB & 3;
#pragma unroll
    for (int dg = 0; dg < 4; dg++) {
        short4v ovA, ovB;
#pragma unroll
        for (int r = 0; r < 4; r++) {
            ovA[r] = f2b(oA[dg][r] * rinvA);
            ovB[r] = f2b(oB[dg][r] * rinvB);
        }
        int lane_o = ((dg & 1) * 2 + (lg >> 1)) * 16 + lr;
        size_t offA = (((RoA * 16 + h) * 2 + (dg >> 1)) * 4 + moA) * 512
                      + (size_t)lane_o * 8 + (lg & 1) * 4;
        size_t offB = (((RoA * 16 + h) * 2 + (dg >> 1)) * 4 + moB) * 512
                      + (size_t)lane_o * 8 + (lg & 1) * 4;
        *reinterpret_cast<short4v*>(Afo + offA) = ovA;
        *reinterpret_cast<short4v*>(Afo + offB) = ovB;
    }
}

extern "C" void kernel_launch(void* const* d_in, const int* in_sizes, int n_in,
                              void* d_out, int out_size, void* d_ws, size_t ws_size,
                              hipStream_t stream) {
    const float* x  = (const float*)d_in[0];
    const float* Wq = (const float*)d_in[1];
    const float* bq = (const float*)d_in[2];
    const float* Wk = (const float*)d_in[3];
    const float* bk = (const float*)d_in[4];
    const float* Wv = (const float*)d_in[5];
    const float* bv = (const float*)d_in[6];
    const float* Wo = (const float*)d_in[7];
    const float* bo = (const float*)d_in[8];

    float* out = (float*)d_out;
    float* presentK = out + (size_t)4194304;
    float* presentV = presentK + (size_t)4194304;

    char* ws = (char*)d_ws;
    short* Af    = (short*)(ws);                        // x in A-frag tiling, 8MB
    short* Bfq   = (short*)(ws + ((size_t)8  << 20));   // W in B-frag tiling, 2MB each
    short* Bfk   = (short*)(ws + ((size_t)10 << 20));
    short* Bfv   = (short*)(ws + ((size_t)12 << 20));
    short* Bfo   = (short*)(ws + ((size_t)14 << 20));
    short* Qb    = (short*)(ws + ((size_t)16 << 20));
    short* Kfrag = (short*)(ws + ((size_t)24 << 20));   // [bh][j][ks][cg][lane][8] bf16, 8MB
    short* Vfrag = (short*)(ws + ((size_t)32 << 20));   // [bh][j][ks][dg][lane][8] bf16, 8MB
    short* Afo   = (short*)(ws + ((size_t)40 << 20));   // attn out in A-frag tiling, 8MB

    k_convert_x<<<dim3(2048), dim3(256), 0, stream>>>(x, Af);
    k_transpose_w4<<<dim3(32, 32, 4), dim3(32, 8), 0, stream>>>(
        Wq, Wk, Wv, Wo, Bfq, Bfk, Bfv, Bfo);
    k_gemm_qkv<<<dim3(768), dim3(256), 0, stream>>>(
        Af, Bfq, Bfk, Bfv, bq, bk, bv, Qb, Kfrag, Vfrag, presentK, presentV);
    k_attn<<<dim3(2048), dim3(64), 0, stream>>>(Qb, Kfrag, Vfrag, Afo);
    k_gemm_o<<<dim3(1024), dim3(64), 0, stream>>>(Afo, Bfo, bo, out);
}

// Round 17
// 115.716 us; speedup vs baseline: 1.2328x; 1.1386x over previous
//
#include <hip/hip_runtime.h>
#include <hip/hip_bf16.h>

typedef __attribute__((ext_vector_type(8))) short short8;
typedef __attribute__((ext_vector_type(4))) short short4v;
typedef __attribute__((ext_vector_type(4))) float f32x4;

#define S_LEN 2048
#define DM 1024
#define NH 16
#define HD 64

__device__ __forceinline__ short f2b(float f) {
    __hip_bfloat16 h = __float2bfloat16(f);
    return *reinterpret_cast<short*>(&h);
}

// ---------------- convert x (fp32 -> bf16) into A-fragment tiling (R10-proven) ----------------
__global__ void k_convert_x(const float* __restrict__ x, short* __restrict__ Af) {
    int t = blockIdx.x * 256 + threadIdx.x;       // 524288 threads: s(4096) x kc(128)
    int s = t >> 7, kc = t & 127;
    const float* xp = x + (size_t)s * DM + kc * 8;
    f32x4 v0 = *reinterpret_cast<const f32x4*>(xp);
    f32x4 v1 = *reinterpret_cast<const f32x4*>(xp + 4);
    short8 o;
    for (int e = 0; e < 4; e++) { o[e] = f2b(v0[e]); o[4 + e] = f2b(v1[e]); }
    int R = s >> 6, m = (s >> 4) & 3, lr = s & 15;
    int kstep = kc >> 3, ks = (kc >> 2) & 1, lg = kc & 3;
    size_t off = ((((size_t)(R * 16 + kstep) * 2 + ks) * 4 + m) * 64 + lg * 16 + lr) * 8;
    *reinterpret_cast<short8*>(Af + off) = o;
}

// ---------------- transpose + convert all four W into B-fragment tiling (R12-proven) ----------------
__global__ void k_transpose_w4(const float* __restrict__ W0, const float* __restrict__ W1,
                               const float* __restrict__ W2, const float* __restrict__ W3,
                               short* __restrict__ T0, short* __restrict__ T1,
                               short* __restrict__ T2, short* __restrict__ T3) {
    __shared__ float tile[32][33];
    const int z = blockIdx.z;
    const float* W = (z == 0) ? W0 : (z == 1) ? W1 : (z == 2) ? W2 : W3;
    short* Wt = (z == 0) ? T0 : (z == 1) ? T1 : (z == 2) ? T2 : T3;
    int tx = threadIdx.x, ty = threadIdx.y;
    int nb = blockIdx.x * 32, kb = blockIdx.y * 32;
    for (int i = 0; i < 4; i++)
        tile[ty + i * 8][tx] = W[(size_t)(kb + ty + i * 8) * DM + nb + tx];
    __syncthreads();
    if (ty < 4) {
        int col = nb + tx;
        int k0 = kb + ty * 8;
        short8 o;
#pragma unroll
        for (int e = 0; e < 8; e++) o[e] = f2b(tile[ty * 8 + e][tx]);
        int C = col >> 6, n = (col >> 4) & 3, lr = col & 15;
        int kstep = k0 >> 6, ksb = (k0 >> 5) & 1, lg = (k0 >> 3) & 3;
        *reinterpret_cast<short8*>(
            &Wt[((((size_t)(C * 16 + kstep) * 2 + ksb) * 4 + n) * 64 + lg * 16 + lr) * 8]) = o;
    }
}

// ---------------- fused QKV GEMM: NO LDS, NO barriers (R10/R13-proven body) ----------------
// C-MAJOR decode: 8 time-adjacent blocks share ONE B-column across 8 R's -> B-column
// becomes L2-hot (leader misses, followers hit); per-kstep live B ~300KB << 4MB L2.
// A stays XCD-chunked: R in [8x, 8x+8).
__global__ __launch_bounds__(64) void k_gemm_qkv(
    const short* __restrict__ Af,
    const short* __restrict__ Bq, const short* __restrict__ Bk, const short* __restrict__ Bv,
    const float* __restrict__ bq, const float* __restrict__ bk, const float* __restrict__ bv,
    short* __restrict__ Qb, short* __restrict__ Kfrag, short* __restrict__ Vfrag,
    float* __restrict__ pK, float* __restrict__ pV)
{
    const int bid = blockIdx.x;
    const int xcd = bid & 7, loc = bid >> 3;         // loc in [0,384) per XCD
    const int zC = loc >> 3, rloc = loc & 7;         // 8 consecutive blocks: same (z,C)
    const int R = xcd * 8 + rloc;
    const int z = zC >> 4, C = zC & 15;
    const short* Bf = (z == 0) ? Bq : (z == 1) ? Bk : Bv;
    const float* bias = (z == 0) ? bq : (z == 1) ? bk : bv;
    const int l = threadIdx.x;
    const int lr = l & 15, lg = l >> 4;

    f32x4 acc[4][4];
#pragma unroll
    for (int m = 0; m < 4; m++)
#pragma unroll
        for (int n = 0; n < 4; n++) acc[m][n] = (f32x4)0.0f;

    const short* ap = Af + (size_t)R * 16 * 4096 + l * 8;
    const short* bp = Bf + (size_t)C * 16 * 4096 + l * 8;

#pragma unroll 1
    for (int kstep = 0; kstep < 16; ++kstep) {
        short8 a[2][4], b[2][4];
#pragma unroll
        for (int ks = 0; ks < 2; ks++)
#pragma unroll
            for (int i = 0; i < 4; i++) {
                a[ks][i] = *reinterpret_cast<const short8*>(ap + (ks * 4 + i) * 512);
                b[ks][i] = *reinterpret_cast<const short8*>(bp + (ks * 4 + i) * 512);
            }
        ap += 4096; bp += 4096;
#pragma unroll
        for (int ks = 0; ks < 2; ks++)
#pragma unroll
            for (int m = 0; m < 4; m++)
#pragma unroll
                for (int n = 0; n < 4; n++)
                    acc[m][n] = __builtin_amdgcn_mfma_f32_16x16x32_bf16(a[ks][m], b[ks][n], acc[m][n], 0, 0, 0);
    }

    for (int m = 0; m < 4; m++)
        for (int n = 0; n < 4; n++) {
            int row = R * 64 + m * 16 + lg * 4;
            int col = C * 64 + n * 16 + lr;
            float bv_ = bias[col];
            int b_ = row >> 11, sI0 = row & 2047, hI = col >> 6, dh = col & 63;
            if (z == 0) {
                for (int r = 0; r < 4; r++) {
                    float v = acc[m][n][r] + bv_;
                    Qb[(size_t)(row + r) * DM + col] = f2b(v * 0.0450842200575152f);  // 1/32*log2(e)
                }
            } else if (z == 1) {
                for (int r = 0; r < 4; r++) {
                    float v = acc[m][n][r] + bv_;
                    int sI = sI0 + r;
                    pK[(((size_t)(b_ * NH + hI)) * S_LEN + sI) * HD + dh] = v;
                    int j = sI >> 6, kk = sI & 63;
                    int cg = ((kk >> 4) & 2) | ((kk >> 2) & 1);
                    int lrA = ((kk >> 3) & 3) * 4 + (kk & 3);
                    int lane = lrA + ((dh >> 3) & 3) * 16;
                    int ks = dh >> 5, e = dh & 7;
                    Kfrag[((((size_t)(b_ * NH + hI) * 32 + j) * 2 + ks) * 4 + cg) * 512
                          + lane * 8 + e] = f2b(v);
                }
            } else {
                int j = sI0 >> 6, ks = (sI0 >> 5) & 1;
                int dg = dh >> 4;
                int lane = (dh & 15) + ((sI0 >> 3) & 3) * 16;
                int e0 = sI0 & 7;
                short4v tv;
                for (int r = 0; r < 4; r++) {
                    float v = acc[m][n][r] + bv_;
                    pV[(((size_t)(b_ * NH + hI)) * S_LEN + (sI0 + r)) * HD + dh] = v;
                    tv[r] = f2b(v);
                }
                *reinterpret_cast<short4v*>(
                    &Vfrag[((((size_t)(b_ * NH + hI) * 32 + j) * 2 + ks) * 4 + dg) * 512
                           + lane * 8 + e0]) = tv;
            }
        }
}

// ---------------- final GEMM: out = attn @ Wo + bo — NO LDS fragment version (R11-proven) ----------------
__global__ __launch_bounds__(64) void k_gemm_o(
    const short* __restrict__ Af, const short* __restrict__ Bf,
    const float* __restrict__ bo, float* __restrict__ out)
{
    const int bid = blockIdx.x;
    const int orig = (bid & 7) * 128 + (bid >> 3);
    const int R = orig >> 4, C = orig & 15;
    const int l = threadIdx.x;
    const int lr = l & 15, lg = l >> 4;

    f32x4 acc[4][4];
#pragma unroll
    for (int m = 0; m < 4; m++)
#pragma unroll
        for (int n = 0; n < 4; n++) acc[m][n] = (f32x4)0.0f;

    const short* ap = Af + (size_t)R * 16 * 4096 + l * 8;
    const short* bp = Bf + (size_t)C * 16 * 4096 + l * 8;

#pragma unroll 1
    for (int kstep = 0; kstep < 16; ++kstep) {
        short8 a[2][4], b[2][4];
#pragma unroll
        for (int ks = 0; ks < 2; ks++)
#pragma unroll
            for (int i = 0; i < 4; i++) {
                a[ks][i] = *reinterpret_cast<const short8*>(ap + (ks * 4 + i) * 512);
                b[ks][i] = *reinterpret_cast<const short8*>(bp + (ks * 4 + i) * 512);
            }
        ap += 4096; bp += 4096;
#pragma unroll
        for (int ks = 0; ks < 2; ks++)
#pragma unroll
            for (int m = 0; m < 4; m++)
#pragma unroll
                for (int n = 0; n < 4; n++)
                    acc[m][n] = __builtin_amdgcn_mfma_f32_16x16x32_bf16(a[ks][m], b[ks][n], acc[m][n], 0, 0, 0);
    }
    for (int m = 0; m < 4; m++)
        for (int n = 0; n < 4; n++) {
            int row = R * 64 + m * 16 + lg * 4;
            int col = C * 64 + n * 16 + lr;
            float bv_ = bo[col];
            for (int r = 0; r < 4; r++)
                out[(size_t)(row + r) * DM + col] = acc[m][n][r] + bv_;
        }
}

// ---------------- causal flash attention: 2 adjacent strips per 1-wave block (R13-proven) ----------------
__global__ __launch_bounds__(64) void k_attn(
    const short* __restrict__ Qb, const short* __restrict__ Kfrag,
    const short* __restrict__ Vfrag, short* __restrict__ Afo)
{
    const int bid = blockIdx.x;
    const int orig = (bid & 7) * 256 + (bid >> 3);   // XCD-chunked: 4 bh per XCD
    const int bh = orig >> 6;
    const int p = 63 - (orig & 63);                  // heavy pairs dispatch first
    const int h = bh & 15, b = bh >> 4;
    const int l = threadIdx.x;
    const int lr = l & 15, lg = l >> 4;
    const short* Qp = Qb + (size_t)b * S_LEN * DM + (size_t)h * HD;
    const short* Kbh = Kfrag + (size_t)bh * 32 * 4096;
    const short* Vbh = Vfrag + (size_t)bh * 32 * 4096;

    const int jmax = p >> 1;
    const int sA = 2 * p, sB = 2 * p + 1;
    const int qrowA = sA * 16 + lr, qrowB = sB * 16 + lr;
    short8 qfA0 = *reinterpret_cast<const short8*>(Qp + (size_t)qrowA * DM + lg * 8);
    short8 qfA1 = *reinterpret_cast<const short8*>(Qp + (size_t)qrowA * DM + 32 + lg * 8);
    short8 qfB0 = *reinterpret_cast<const short8*>(Qp + (size_t)qrowB * DM + lg * 8);
    short8 qfB1 = *reinterpret_cast<const short8*>(Qp + (size_t)qrowB * DM + 32 + lg * 8);
    f32x4 oA[4], oB[4];
#pragma unroll
    for (int dg = 0; dg < 4; dg++) { oA[dg] = (f32x4)0.0f; oB[dg] = (f32x4)0.0f; }
    float lrunA = 0.0f, lrunB = 0.0f;

    const short* kp = Kbh + l * 8;
    const short* vp = Vbh + l * 8;
    short8 kc[2][4], vc[2][4];
#pragma unroll
    for (int ks = 0; ks < 2; ks++)
#pragma unroll
        for (int cg = 0; cg < 4; cg++) {
            kc[ks][cg] = *reinterpret_cast<const short8*>(kp + (ks * 4 + cg) * 512);
            vc[ks][cg] = *reinterpret_cast<const short8*>(vp + (ks * 4 + cg) * 512);
        }

    for (int j = 0; j <= jmax; ++j) {
        f32x4 sAcc[4], sBcc[4];
#pragma unroll
        for (int cg = 0; cg < 4; cg++) { sAcc[cg] = (f32x4)0.0f; sBcc[cg] = (f32x4)0.0f; }
#pragma unroll
        for (int ks = 0; ks < 2; ks++) {
            const short8 qfa = ks ? qfA1 : qfA0;
            const short8 qfb = ks ? qfB1 : qfB0;
#pragma unroll
            for (int cg = 0; cg < 4; cg++) {
                sAcc[cg] = __builtin_amdgcn_mfma_f32_16x16x32_bf16(kc[ks][cg], qfa, sAcc[cg], 0, 0, 0);
                sBcc[cg] = __builtin_amdgcn_mfma_f32_16x16x32_bf16(kc[ks][cg], qfb, sBcc[cg], 0, 0, 0);
            }
        }
        if (j < jmax) {
            kp += 4096;
#pragma unroll
            for (int ks = 0; ks < 2; ks++)
#pragma unroll
                for (int cg = 0; cg < 4; cg++)
                    kc[ks][cg] = *reinterpret_cast<const short8*>(kp + (ks * 4 + cg) * 512);
        }
        if (j == jmax) {
#pragma unroll
            for (int cg = 0; cg < 4; cg++)
#pragma unroll
                for (int r = 0; r < 4; r++) {
                    int n = ((cg >> 1) << 5) + (lg << 3) + ((cg & 1) << 2) + r;
                    if (j * 64 + n > qrowA) sAcc[cg][r] = -INFINITY;
                    if (j * 64 + n > qrowB) sBcc[cg][r] = -INFINITY;
                }
        }
        float rsA = 0.0f, rsB = 0.0f;
#pragma unroll
        for (int cg = 0; cg < 4; cg++)
#pragma unroll
            for (int r = 0; r < 4; r++) {
                float pa = __builtin_amdgcn_exp2f(sAcc[cg][r]);
                float pb = __builtin_amdgcn_exp2f(sBcc[cg][r]);
                sAcc[cg][r] = pa; sBcc[cg][r] = pb;
                rsA += pa; rsB += pb;
            }
        lrunA += rsA; lrunB += rsB;
        short8 pfA0, pfA1, pfB0, pfB1;
#pragma unroll
        for (int r = 0; r < 4; r++) {
            pfA0[r] = f2b(sAcc[0][r]); pfA0[4 + r] = f2b(sAcc[1][r]);
            pfA1[r] = f2b(sAcc[2][r]); pfA1[4 + r] = f2b(sAcc[3][r]);
            pfB0[r] = f2b(sBcc[0][r]); pfB0[4 + r] = f2b(sBcc[1][r]);
            pfB1[r] = f2b(sBcc[2][r]); pfB1[4 + r] = f2b(sBcc[3][r]);
        }
#pragma unroll
        for (int ks = 0; ks < 2; ks++) {
            const short8 pfa = ks ? pfA1 : pfA0;
            const short8 pfb = ks ? pfB1 : pfB0;
#pragma unroll
            for (int dg = 0; dg < 4; dg++) {
                oA[dg] = __builtin_amdgcn_mfma_f32_16x16x32_bf16(vc[ks][dg], pfa, oA[dg], 0, 0, 0);
                oB[dg] = __builtin_amdgcn_mfma_f32_16x16x32_bf16(vc[ks][dg], pfb, oB[dg], 0, 0, 0);
            }
        }
        if (j < jmax) {
            vp += 4096;
#pragma unroll
            for (int ks = 0; ks < 2; ks++)
#pragma unroll
                for (int cg = 0; cg < 4; cg++)
                    vc[ks][cg] = *reinterpret_cast<const short8*>(vp + (ks * 4 + cg) * 512);
        }
    }
    lrunA += __shfl_xor(lrunA, 16); lrunA += __shfl_xor(lrunA, 32);
    lrunB += __shfl_xor(lrunB, 16); lrunB += __shfl_xor(lrunB, 32);
    float rinvA = 1.0f / lrunA, rinvB = 1.0f / lrunB;
    const size_t RoA = (size_t)(b * 32 + (sA >> 2));
    const int moA = sA & 3, moB = sB & 3;
#pragma unroll
    for (int dg = 0; dg < 4; dg++) {
        short4v ovA, ovB;
#pragma unroll
        for (int r = 0; r < 4; r++) {
            ovA[r] = f2b(oA[dg][r] * rinvA);
            ovB[r] = f2b(oB[dg][r] * rinvB);
        }
        int lane_o = ((dg & 1) * 2 + (lg >> 1)) * 16 + lr;
        size_t offA = (((RoA * 16 + h) * 2 + (dg >> 1)) * 4 + moA) * 512
                      + (size_t)lane_o * 8 + (lg & 1) * 4;
        size_t offB = (((RoA * 16 + h) * 2 + (dg >> 1)) * 4 + moB) * 512
                      + (size_t)lane_o * 8 + (lg & 1) * 4;
        *reinterpret_cast<short4v*>(Afo + offA) = ovA;
        *reinterpret_cast<short4v*>(Afo + offB) = ovB;
    }
}

extern "C" void kernel_launch(void* const* d_in, const int* in_sizes, int n_in,
                              void* d_out, int out_size, void* d_ws, size_t ws_size,
                              hipStream_t stream) {
    const float* x  = (const float*)d_in[0];
    const float* Wq = (const float*)d_in[1];
    const float* bq = (const float*)d_in[2];
    const float* Wk = (const float*)d_in[3];
    const float* bk = (const float*)d_in[4];
    const float* Wv = (const float*)d_in[5];
    const float* bv = (const float*)d_in[6];
    const float* Wo = (const float*)d_in[7];
    const float* bo = (const float*)d_in[8];

    float* out = (float*)d_out;
    float* presentK = out + (size_t)4194304;
    float* presentV = presentK + (size_t)4194304;

    char* ws = (char*)d_ws;
    short* Af    = (short*)(ws);                        // x in A-frag tiling, 8MB
    short* Bfq   = (short*)(ws + ((size_t)8  << 20));   // W in B-frag tiling, 2MB each
    short* Bfk   = (short*)(ws + ((size_t)10 << 20));
    short* Bfv   = (short*)(ws + ((size_t)12 << 20));
    short* Bfo   = (short*)(ws + ((size_t)14 << 20));
    short* Qb    = (short*)(ws + ((size_t)16 << 20));
    short* Kfrag = (short*)(ws + ((size_t)24 << 20));   // [bh][j][ks][cg][lane][8] bf16, 8MB
    short* Vfrag = (short*)(ws + ((size_t)32 << 20));   // [bh][j][ks][dg][lane][8] bf16, 8MB
    short* Afo   = (short*)(ws + ((size_t)40 << 20));   // attn out in A-frag tiling, 8MB

    k_convert_x<<<dim3(2048), dim3(256), 0, stream>>>(x, Af);
    k_transpose_w4<<<dim3(32, 32, 4), dim3(32, 8), 0, stream>>>(
        Wq, Wk, Wv, Wo, Bfq, Bfk, Bfv, Bfo);
    k_gemm_qkv<<<dim3(3072), dim3(64), 0, stream>>>(
        Af, Bfq, Bfk, Bfv, bq, bk, bv, Qb, Kfrag, Vfrag, presentK, presentV);
    k_attn<<<dim3(2048), dim3(64), 0, stream>>>(Qb, Kfrag, Vfrag, Afo);
    k_gemm_o<<<dim3(1024), dim3(64), 0, stream>>>(Afo, Bfo, bo, out);
}